// Round 4
// baseline (195.040 us; speedup 1.0000x reference)
//
#include <hip/hip_runtime.h>
#include <math.h>

#define Bn   128
#define Rn   1152
#define CIn  8
#define Cn   10
#define On   16
#define BO   2048      // Bn*On
#define CBO  20480     // Cn*BO
#define PSEG 72        // partial segments per (c,b,o); block = (c, segq), 16 r per block
#define LSTR 20        // LDS row stride (floats): 16 + 4 pad -> 2-way banks (free)

// F4 helpers (component-wise)
#define F4SET0(a)      a.x=0.f; a.y=0.f; a.z=0.f; a.w=0.f
#define F4FMA(acc,s,v) acc.x=fmaf(s,v.x,acc.x); acc.y=fmaf(s,v.y,acc.y); \
                       acc.z=fmaf(s,v.z,acc.z); acc.w=fmaf(s,v.w,acc.w)

// ---- transpose x[b][r][i] -> XT[r][g][b][q]  (i = g*4+q), float4 units
__global__ __launch_bounds__(256)
void transpose_x(const float* __restrict__ X, float* __restrict__ XT)
{
    const int r = blockIdx.x;
    const int b = threadIdx.x & 127;
    const int g = threadIdx.x >> 7;
    float4 v = *(const float4*)(X + (size_t)b * (Rn * CIn) + r * CIn + g * 4);
    ((float4*)XT)[r * 256 + g * 128 + b] = v;
}

// ---- pass kernel
// Lane (64) = bq(16) x og(4). Thread owns b = bh*64 + j*16 + bq (j<4),
// o = og*4 + q (q<4). Wave = (bh, rsub) within block; block = (c, segq).
// Per wave: 8 r. W loads are divergent float4 VMEM (no SGPR pressure);
// 128 FMA per r per thread covers load latency.
// Grid: 720 = Cn(10) * PSEG(72)
template<int PASS>
__global__ __launch_bounds__(256, 3)
void pass_kernel(const float* __restrict__ XT, const float* __restrict__ W,
                 const float* __restrict__ Sprev, const float* __restrict__ N2,
                 float* __restrict__ PT, float* __restrict__ PL)
{
    __shared__ float ldsT[2][64 * LSTR];   // 10.2 KB
    __shared__ float ldsL[2][64 * LSTR];   // 10.2 KB

    const int blk  = blockIdx.x;
    const int c    = blk / PSEG;
    const int segq = blk - c * PSEG;
    const int tid  = threadIdx.x;
    const int wv   = tid >> 6;
    const int bh   = wv & 1;
    const int rsub = wv >> 1;
    const int lane = tid & 63;
    const int bq   = lane & 15;
    const int og   = lane >> 4;
    const int r0   = segq * 16 + rsub * 8;

    // per-thread Vsum (pre-scaled by log2e) from previous passes
    float4 vs[4];
    if (PASS > 1) {
        float coef[PASS];
        #pragma unroll
        for (int t = 0; t < PASS - 1; ++t) {
            const float n2 = N2[t];
            coef[t] = n2 / ((1.0f + n2) * sqrtf(n2)) * 1.4426950408889634f;
        }
        #pragma unroll
        for (int j = 0; j < 4; ++j) {
            const int b = bh * 64 + j * 16 + bq;
            float4 a; F4SET0(a);
            #pragma unroll
            for (int t = 0; t < PASS - 1; ++t) {
                const float4 s4 = *(const float4*)(Sprev + t * CBO + c * BO + b * On + og * 4);
                F4FMA(a, coef[t], s4);
            }
            vs[j] = a;
        }
    }

    float4 tacc[4], lacc[4];
    #pragma unroll
    for (int j = 0; j < 4; ++j) { F4SET0(tacc[j]); F4SET0(lacc[j]); }

    const float4* XT4 = (const float4*)XT;
    const float*  wc  = W + (size_t)c * Rn * 128;

    #pragma unroll
    for (int rr = 0; rr < 8; ++rr) {
        const int r = r0 + rr;
        // W fragment: 8 float4, divergent by og -> vector loads
        float4 wf[8];
        #pragma unroll
        for (int i = 0; i < 8; ++i)
            wf[i] = *(const float4*)(wc + r * 128 + i * On + og * 4);
        // x fragments: 4 b x 8 i, coalesced across bq
        float4 xa[4], xb[4];
        #pragma unroll
        for (int j = 0; j < 4; ++j) {
            const int b = bh * 64 + j * 16 + bq;
            xa[j] = XT4[r * 256 + b];
            xb[j] = XT4[r * 256 + 128 + b];
        }
        #pragma unroll
        for (int j = 0; j < 4; ++j) {
            float4 u;
            u.x = xa[j].x * wf[0].x; u.y = xa[j].x * wf[0].y;
            u.z = xa[j].x * wf[0].z; u.w = xa[j].x * wf[0].w;
            F4FMA(u, xa[j].y, wf[1]);
            F4FMA(u, xa[j].z, wf[2]);
            F4FMA(u, xa[j].w, wf[3]);
            F4FMA(u, xb[j].x, wf[4]);
            F4FMA(u, xb[j].y, wf[5]);
            F4FMA(u, xb[j].z, wf[6]);
            F4FMA(u, xb[j].w, wf[7]);
            if (PASS == 1) {
                tacc[j].x += u.x; tacc[j].y += u.y;
                tacc[j].z += u.z; tacc[j].w += u.w;
            } else {
                float4 e;
                e.x = exp2f(u.x * vs[j].x);
                e.y = exp2f(u.y * vs[j].y);
                e.z = exp2f(u.z * vs[j].z);
                e.w = exp2f(u.w * vs[j].w);
                lacc[j].x += e.x; lacc[j].y += e.y;
                lacc[j].z += e.z; lacc[j].w += e.w;
                tacc[j].x = fmaf(e.x, u.x, tacc[j].x);
                tacc[j].y = fmaf(e.y, u.y, tacc[j].y);
                tacc[j].z = fmaf(e.z, u.z, tacc[j].z);
                tacc[j].w = fmaf(e.w, u.w, tacc[j].w);
            }
        }
    }

    // ---- cross-wave (rsub) reduce via LDS, single barrier, then store partials
    if (rsub == 1) {
        #pragma unroll
        for (int j = 0; j < 4; ++j) {
            const int row = (j * 16 + bq) * LSTR + og * 4;
            *(float4*)&ldsT[bh][row] = tacc[j];
            if (PASS > 1) *(float4*)&ldsL[bh][row] = lacc[j];
        }
    }
    __syncthreads();
    if (rsub == 0) {
        #pragma unroll
        for (int j = 0; j < 4; ++j) {
            const int row = (j * 16 + bq) * LSTR + og * 4;
            const float4 ot = *(const float4*)&ldsT[bh][row];
            tacc[j].x += ot.x; tacc[j].y += ot.y;
            tacc[j].z += ot.z; tacc[j].w += ot.w;
            const int b   = bh * 64 + j * 16 + bq;
            const int idx = segq * CBO + c * BO + b * On + og * 4;
            *(float4*)(PT + idx) = tacc[j];
            if (PASS > 1) {
                const float4 ol = *(const float4*)&ldsL[bh][row];
                lacc[j].x += ol.x; lacc[j].y += ol.y;
                lacc[j].z += ol.z; lacc[j].w += ol.w;
                *(float4*)(PL + idx) = lacc[j];
            }
        }
    }
}

// sum partials over PSEG segs; s = T/L; store S slot; reduce sum(s^2) -> N2 slot
template<int PASS>
__global__ __launch_bounds__(256)
void combine_kernel(const float* __restrict__ PT, const float* __restrict__ PL,
                    float* __restrict__ Sout, float* __restrict__ n2out)
{
    const int i = blockIdx.x * 256 + threadIdx.x;   // 80 blocks * 256 = 20480
    float T = 0.0f, L = 0.0f;
    #pragma unroll
    for (int s = 0; s < PSEG; ++s) T += PT[s * CBO + i];
    if (PASS == 1) {
        L = (float)Rn;   // exp(0)=1 summed over all r
    } else {
        #pragma unroll
        for (int s = 0; s < PSEG; ++s) L += PL[s * CBO + i];
    }
    const float sv = T / L;
    Sout[i] = sv;
    float sq = sv * sv;
    #pragma unroll
    for (int d = 1; d < 64; d <<= 1) sq += __shfl_xor(sq, d);
    __shared__ float red[4];
    if ((threadIdx.x & 63) == 0) red[threadIdx.x >> 6] = sq;
    __syncthreads();
    if (threadIdx.x == 0)
        atomicAdd(n2out, red[0] + red[1] + red[2] + red[3]);
}

__global__ __launch_bounds__(256)
void final_kernel(const float* __restrict__ S, const float* __restrict__ n2p,
                  float* __restrict__ out)
{
    const int i = blockIdx.x * 256 + threadIdx.x;
    const float n2 = *n2p;
    const float coef = n2 / ((1.0f + n2) * sqrtf(n2));
    out[i] = coef * S[i];
}

extern "C" void kernel_launch(void* const* d_in, const int* in_sizes, int n_in,
                              void* d_out, int out_size, void* d_ws, size_t ws_size,
                              hipStream_t stream)
{
    const float* X = (const float*)d_in[0];
    const float* W = (const float*)d_in[1];
    float* ws = (float*)d_ws;
    float* XT = ws;                          // Rn*Bn*CIn = 1,179,648 floats
    float* N2 = XT + Rn * Bn * CIn;          // 4 floats
    float* PT = N2 + 4;                      // PSEG*CBO = 1,474,560 floats
    float* PL = PT + PSEG * CBO;             // PSEG*CBO
    float* S  = PL + PSEG * CBO;             // 3*CBO

    hipMemsetAsync(N2, 0, 16, stream);       // zero n^2 accumulators only

    transpose_x<<<Rn, 256, 0, stream>>>(X, XT);
    pass_kernel<1><<<720, 256, 0, stream>>>(XT, W, S, N2, PT, PL);
    combine_kernel<1><<<80, 256, 0, stream>>>(PT, PL, S + 0 * CBO, N2 + 0);
    pass_kernel<2><<<720, 256, 0, stream>>>(XT, W, S, N2, PT, PL);
    combine_kernel<2><<<80, 256, 0, stream>>>(PT, PL, S + 1 * CBO, N2 + 1);
    pass_kernel<3><<<720, 256, 0, stream>>>(XT, W, S, N2, PT, PL);
    combine_kernel<3><<<80, 256, 0, stream>>>(PT, PL, S + 2 * CBO, N2 + 2);
    final_kernel<<<80, 256, 0, stream>>>(S + 2 * CBO, N2 + 2, (float*)d_out);
}

// Round 5
// 173.304 us; speedup vs baseline: 1.1254x; 1.1254x over previous
//
#include <hip/hip_runtime.h>
#include <math.h>

#define Bn   128
#define Rn   1152
#define CIn  8
#define Cn   10
#define On   16
#define BO   2048      // Bn*On
#define CBO  20480     // Cn*BO
#define RB   12        // r's per block
#define PSEG 96        // Rn / RB partial segments

#define F4SET0(a)      a.x=0.f; a.y=0.f; a.z=0.f; a.w=0.f
#define F4FMA(acc,s,v) acc.x=fmaf(s,v.x,acc.x); acc.y=fmaf(s,v.y,acc.y); \
                       acc.z=fmaf(s,v.z,acc.z); acc.w=fmaf(s,v.w,acc.w)

// ---- transpose x[b][r][i] -> XT[r][g][b][q]  (i = g*4+q), float4 units
__global__ __launch_bounds__(256)
void transpose_x(const float* __restrict__ X, float* __restrict__ XT)
{
    const int r = blockIdx.x;
    const int b = threadIdx.x & 127;
    const int g = threadIdx.x >> 7;
    float4 v = *(const float4*)(X + (size_t)b * (Rn * CIn) + r * CIn + g * 4);
    ((float4*)XT)[r * 256 + g * 128 + b] = v;
}

// ---- pass kernel: no LDS, no barriers, spill-proof register budget
// Block = (c, seg of 12 r). 4 waves = 4 b-quarters (32 b each).
// Lane = og(4)<<4 | bq(16). Thread owns b = wv*32 + j*16 + bq (j<2),
// o = og*4+q (q<4); accumulates its (b,o) tile over the block's 12 r's
// entirely in registers, then stores one partial per (seg, c, b, o).
// Grid: 960 = Cn(10) * PSEG(96)  -> ~15 waves/CU resident.
template<int PASS>
__global__ __launch_bounds__(256, 4)
void pass_kernel(const float* __restrict__ XT, const float* __restrict__ W,
                 const float* __restrict__ Sprev, const float* __restrict__ N2,
                 float* __restrict__ PT, float* __restrict__ PL)
{
    const int blk  = blockIdx.x;
    const int c    = blk / PSEG;
    const int seg  = blk - c * PSEG;
    const int tid  = threadIdx.x;
    const int wv   = tid >> 6;
    const int lane = tid & 63;
    const int bq   = lane & 15;
    const int og   = lane >> 4;
    const int r0   = seg * RB;

    // per-thread Vsum (pre-scaled by log2e) from previous passes
    float4 vs[2];
    if (PASS > 1) {
        float coef[PASS];
        #pragma unroll
        for (int t = 0; t < PASS - 1; ++t) {
            const float n2 = N2[t];
            coef[t] = n2 / ((1.0f + n2) * sqrtf(n2)) * 1.4426950408889634f;
        }
        #pragma unroll
        for (int j = 0; j < 2; ++j) {
            const int b = wv * 32 + j * 16 + bq;
            float4 a; F4SET0(a);
            #pragma unroll
            for (int t = 0; t < PASS - 1; ++t) {
                const float4 s4 = *(const float4*)(Sprev + t * CBO + c * BO + b * On + og * 4);
                F4FMA(a, coef[t], s4);
            }
            vs[j] = a;
        }
    }

    float4 tacc[2], lacc[2];
    #pragma unroll
    for (int j = 0; j < 2; ++j) { F4SET0(tacc[j]); F4SET0(lacc[j]); }

    const float4* XT4 = (const float4*)XT;
    const float*  wc  = W + (size_t)c * Rn * 128 + (size_t)r0 * 128 + og * 4;

    #pragma unroll 2
    for (int rr = 0; rr < RB; ++rr) {
        // W fragment: 8 float4; 16 bq-lanes broadcast, 4 og chunks in one 64B line
        const float* wr = wc + rr * 128;
        float4 wf[8];
        #pragma unroll
        for (int i = 0; i < 8; ++i)
            wf[i] = *(const float4*)(wr + i * On);
        // x fragments: coalesced over bq
        float4 xa[2], xb[2];
        #pragma unroll
        for (int j = 0; j < 2; ++j) {
            const int b = wv * 32 + j * 16 + bq;
            xa[j] = XT4[(r0 + rr) * 256 + b];
            xb[j] = XT4[(r0 + rr) * 256 + 128 + b];
        }
        #pragma unroll
        for (int j = 0; j < 2; ++j) {
            float4 u;
            u.x = xa[j].x * wf[0].x; u.y = xa[j].x * wf[0].y;
            u.z = xa[j].x * wf[0].z; u.w = xa[j].x * wf[0].w;
            F4FMA(u, xa[j].y, wf[1]);
            F4FMA(u, xa[j].z, wf[2]);
            F4FMA(u, xa[j].w, wf[3]);
            F4FMA(u, xb[j].x, wf[4]);
            F4FMA(u, xb[j].y, wf[5]);
            F4FMA(u, xb[j].z, wf[6]);
            F4FMA(u, xb[j].w, wf[7]);
            if (PASS == 1) {
                tacc[j].x += u.x; tacc[j].y += u.y;
                tacc[j].z += u.z; tacc[j].w += u.w;
            } else {
                float4 e;
                e.x = exp2f(u.x * vs[j].x);
                e.y = exp2f(u.y * vs[j].y);
                e.z = exp2f(u.z * vs[j].z);
                e.w = exp2f(u.w * vs[j].w);
                lacc[j].x += e.x; lacc[j].y += e.y;
                lacc[j].z += e.z; lacc[j].w += e.w;
                tacc[j].x = fmaf(e.x, u.x, tacc[j].x);
                tacc[j].y = fmaf(e.y, u.y, tacc[j].y);
                tacc[j].z = fmaf(e.z, u.z, tacc[j].z);
                tacc[j].w = fmaf(e.w, u.w, tacc[j].w);
            }
        }
    }

    #pragma unroll
    for (int j = 0; j < 2; ++j) {
        const int b   = wv * 32 + j * 16 + bq;
        const int idx = seg * CBO + c * BO + b * On + og * 4;
        *(float4*)(PT + idx) = tacc[j];
        if (PASS > 1) *(float4*)(PL + idx) = lacc[j];
    }
}

// sum partials over PSEG segs; s = T/L; store S slot; reduce sum(s^2) -> N2 slot
template<int PASS>
__global__ __launch_bounds__(256)
void combine_kernel(const float* __restrict__ PT, const float* __restrict__ PL,
                    float* __restrict__ Sout, float* __restrict__ n2out)
{
    const int i = blockIdx.x * 256 + threadIdx.x;   // 80 blocks * 256 = 20480
    float T = 0.0f, L = 0.0f;
    #pragma unroll 8
    for (int s = 0; s < PSEG; ++s) T += PT[s * CBO + i];
    if (PASS == 1) {
        L = (float)Rn;   // exp(0)=1 summed over all r
    } else {
        #pragma unroll 8
        for (int s = 0; s < PSEG; ++s) L += PL[s * CBO + i];
    }
    const float sv = T / L;
    Sout[i] = sv;
    float sq = sv * sv;
    #pragma unroll
    for (int d = 1; d < 64; d <<= 1) sq += __shfl_xor(sq, d);
    __shared__ float red[4];
    if ((threadIdx.x & 63) == 0) red[threadIdx.x >> 6] = sq;
    __syncthreads();
    if (threadIdx.x == 0)
        atomicAdd(n2out, red[0] + red[1] + red[2] + red[3]);
}

__global__ __launch_bounds__(256)
void final_kernel(const float* __restrict__ S, const float* __restrict__ n2p,
                  float* __restrict__ out)
{
    const int i = blockIdx.x * 256 + threadIdx.x;
    const float n2 = *n2p;
    const float coef = n2 / ((1.0f + n2) * sqrtf(n2));
    out[i] = coef * S[i];
}

extern "C" void kernel_launch(void* const* d_in, const int* in_sizes, int n_in,
                              void* d_out, int out_size, void* d_ws, size_t ws_size,
                              hipStream_t stream)
{
    const float* X = (const float*)d_in[0];
    const float* W = (const float*)d_in[1];
    float* ws = (float*)d_ws;
    float* XT = ws;                          // Rn*Bn*CIn = 1,179,648 floats
    float* N2 = XT + Rn * Bn * CIn;          // 4 floats
    float* PT = N2 + 4;                      // PSEG*CBO = 1,966,080 floats
    float* PL = PT + PSEG * CBO;             // PSEG*CBO
    float* S  = PL + PSEG * CBO;             // 3*CBO

    hipMemsetAsync(N2, 0, 16, stream);       // zero n^2 accumulators only

    transpose_x<<<Rn, 256, 0, stream>>>(X, XT);
    pass_kernel<1><<<960, 256, 0, stream>>>(XT, W, S, N2, PT, PL);
    combine_kernel<1><<<80, 256, 0, stream>>>(PT, PL, S + 0 * CBO, N2 + 0);
    pass_kernel<2><<<960, 256, 0, stream>>>(XT, W, S, N2, PT, PL);
    combine_kernel<2><<<80, 256, 0, stream>>>(PT, PL, S + 1 * CBO, N2 + 1);
    pass_kernel<3><<<960, 256, 0, stream>>>(XT, W, S, N2, PT, PL);
    combine_kernel<3><<<80, 256, 0, stream>>>(PT, PL, S + 2 * CBO, N2 + 2);
    final_kernel<<<80, 256, 0, stream>>>(S + 2 * CBO, N2 + 2, (float*)d_out);
}

// Round 6
// 172.918 us; speedup vs baseline: 1.1279x; 1.0022x over previous
//
#include <hip/hip_runtime.h>
#include <math.h>

#define Bn   128
#define Rn   1152
#define CIn  8
#define Cn   10
#define On   16
#define BO   2048      // Bn*On
#define CBO  20480     // Cn*BO
#define RB   12        // r's per block
#define PSEG 96        // Rn / RB partial segments

#define F4SET0(a)      a.x=0.f; a.y=0.f; a.z=0.f; a.w=0.f
#define F4FMA(acc,s,v) acc.x=fmaf(s,v.x,acc.x); acc.y=fmaf(s,v.y,acc.y); \
                       acc.z=fmaf(s,v.z,acc.z); acc.w=fmaf(s,v.w,acc.w)

// ---- transpose x[b][r][i] -> XT[r][g][b][q]  (i = g*4+q), float4 units
__global__ __launch_bounds__(256)
void transpose_x(const float* __restrict__ X, float* __restrict__ XT)
{
    const int r = blockIdx.x;
    const int b = threadIdx.x & 127;
    const int g = threadIdx.x >> 7;
    float4 v = *(const float4*)(X + (size_t)b * (Rn * CIn) + r * CIn + g * 4);
    ((float4*)XT)[r * 256 + g * 128 + b] = v;
}

// ---- pass kernel: no LDS, no barriers, NO VGPR cap (spills are the enemy)
// Block = (c, seg of 12 r). 4 waves = 4 b-quarters (32 b each).
// Lane = og(4)<<4 | bq(16). Thread owns b = wv*32 + j*16 + bq (j<2),
// o = og*4+q (q<4); accumulates over the block's 12 r's in registers,
// stores one partial per (seg, c, b, o). Grid: 960 = Cn(10) * PSEG(96).
template<int PASS>
__global__ __launch_bounds__(256)
void pass_kernel(const float* __restrict__ XT, const float* __restrict__ W,
                 const float* __restrict__ Sprev, const float* __restrict__ N2,
                 float* __restrict__ PT, float* __restrict__ PL)
{
    const int blk  = blockIdx.x;
    const int c    = blk / PSEG;
    const int seg  = blk - c * PSEG;
    const int tid  = threadIdx.x;
    const int wv   = tid >> 6;
    const int lane = tid & 63;
    const int bq   = lane & 15;
    const int og   = lane >> 4;
    const int r0   = seg * RB;

    // per-thread Vsum (pre-scaled by log2e) from previous passes
    float4 vs[2];
    if (PASS > 1) {
        float coef[PASS];
        #pragma unroll
        for (int t = 0; t < PASS - 1; ++t) {
            const float n2 = N2[t];
            coef[t] = n2 / ((1.0f + n2) * sqrtf(n2)) * 1.4426950408889634f;
        }
        #pragma unroll
        for (int j = 0; j < 2; ++j) {
            const int b = wv * 32 + j * 16 + bq;
            float4 a; F4SET0(a);
            #pragma unroll
            for (int t = 0; t < PASS - 1; ++t) {
                const float4 s4 = *(const float4*)(Sprev + t * CBO + c * BO + b * On + og * 4);
                F4FMA(a, coef[t], s4);
            }
            vs[j] = a;
        }
    }

    float4 tacc[2], lacc[2];
    #pragma unroll
    for (int j = 0; j < 2; ++j) { F4SET0(tacc[j]); F4SET0(lacc[j]); }

    const float4* XT4 = (const float4*)XT;
    const float*  wc  = W + (size_t)c * Rn * 128 + (size_t)r0 * 128 + og * 4;

    #pragma unroll 2
    for (int rr = 0; rr < RB; ++rr) {
        const float* wr = wc + rr * 128;
        // x fragments first (longest-latency), coalesced over bq
        float4 xa[2], xb[2];
        #pragma unroll
        for (int j = 0; j < 2; ++j) {
            const int b = wv * 32 + j * 16 + bq;
            xa[j] = XT4[(r0 + rr) * 256 + b];
            xb[j] = XT4[(r0 + rr) * 256 + 128 + b];
        }
        // W first half: wf[0..3] (one 64B line each, wave-broadcast)
        float4 wf0, wf1, wf2, wf3;
        wf0 = *(const float4*)(wr + 0 * On);
        wf1 = *(const float4*)(wr + 1 * On);
        wf2 = *(const float4*)(wr + 2 * On);
        wf3 = *(const float4*)(wr + 3 * On);
        float4 u[2];
        #pragma unroll
        for (int j = 0; j < 2; ++j) {
            u[j].x = xa[j].x * wf0.x; u[j].y = xa[j].x * wf0.y;
            u[j].z = xa[j].x * wf0.z; u[j].w = xa[j].x * wf0.w;
            F4FMA(u[j], xa[j].y, wf1);
            F4FMA(u[j], xa[j].z, wf2);
            F4FMA(u[j], xa[j].w, wf3);
        }
        // W second half: wf[4..7]
        wf0 = *(const float4*)(wr + 4 * On);
        wf1 = *(const float4*)(wr + 5 * On);
        wf2 = *(const float4*)(wr + 6 * On);
        wf3 = *(const float4*)(wr + 7 * On);
        #pragma unroll
        for (int j = 0; j < 2; ++j) {
            F4FMA(u[j], xb[j].x, wf0);
            F4FMA(u[j], xb[j].y, wf1);
            F4FMA(u[j], xb[j].z, wf2);
            F4FMA(u[j], xb[j].w, wf3);
            if (PASS == 1) {
                tacc[j].x += u[j].x; tacc[j].y += u[j].y;
                tacc[j].z += u[j].z; tacc[j].w += u[j].w;
            } else {
                float4 e;
                e.x = exp2f(u[j].x * vs[j].x);
                e.y = exp2f(u[j].y * vs[j].y);
                e.z = exp2f(u[j].z * vs[j].z);
                e.w = exp2f(u[j].w * vs[j].w);
                lacc[j].x += e.x; lacc[j].y += e.y;
                lacc[j].z += e.z; lacc[j].w += e.w;
                tacc[j].x = fmaf(e.x, u[j].x, tacc[j].x);
                tacc[j].y = fmaf(e.y, u[j].y, tacc[j].y);
                tacc[j].z = fmaf(e.z, u[j].z, tacc[j].z);
                tacc[j].w = fmaf(e.w, u[j].w, tacc[j].w);
            }
        }
    }

    #pragma unroll
    for (int j = 0; j < 2; ++j) {
        const int b   = wv * 32 + j * 16 + bq;
        const int idx = seg * CBO + c * BO + b * On + og * 4;
        *(float4*)(PT + idx) = tacc[j];
        if (PASS > 1) *(float4*)(PL + idx) = lacc[j];
    }
}

// sum partials over PSEG segs; s = T/L; store S slot; reduce sum(s^2) -> N2 slot
template<int PASS>
__global__ __launch_bounds__(256)
void combine_kernel(const float* __restrict__ PT, const float* __restrict__ PL,
                    float* __restrict__ Sout, float* __restrict__ n2out)
{
    const int i = blockIdx.x * 256 + threadIdx.x;   // 80 blocks * 256 = 20480
    float T = 0.0f, L = 0.0f;
    #pragma unroll 8
    for (int s = 0; s < PSEG; ++s) T += PT[s * CBO + i];
    if (PASS == 1) {
        L = (float)Rn;   // exp(0)=1 summed over all r
    } else {
        #pragma unroll 8
        for (int s = 0; s < PSEG; ++s) L += PL[s * CBO + i];
    }
    const float sv = T / L;
    Sout[i] = sv;
    float sq = sv * sv;
    #pragma unroll
    for (int d = 1; d < 64; d <<= 1) sq += __shfl_xor(sq, d);
    __shared__ float red[4];
    if ((threadIdx.x & 63) == 0) red[threadIdx.x >> 6] = sq;
    __syncthreads();
    if (threadIdx.x == 0)
        atomicAdd(n2out, red[0] + red[1] + red[2] + red[3]);
}

__global__ __launch_bounds__(256)
void final_kernel(const float* __restrict__ S, const float* __restrict__ n2p,
                  float* __restrict__ out)
{
    const int i = blockIdx.x * 256 + threadIdx.x;
    const float n2 = *n2p;
    const float coef = n2 / ((1.0f + n2) * sqrtf(n2));
    out[i] = coef * S[i];
}

extern "C" void kernel_launch(void* const* d_in, const int* in_sizes, int n_in,
                              void* d_out, int out_size, void* d_ws, size_t ws_size,
                              hipStream_t stream)
{
    const float* X = (const float*)d_in[0];
    const float* W = (const float*)d_in[1];
    float* ws = (float*)d_ws;
    float* XT = ws;                          // Rn*Bn*CIn = 1,179,648 floats
    float* N2 = XT + Rn * Bn * CIn;          // 4 floats
    float* PT = N2 + 4;                      // PSEG*CBO = 1,966,080 floats
    float* PL = PT + PSEG * CBO;             // PSEG*CBO
    float* S  = PL + PSEG * CBO;             // 3*CBO

    hipMemsetAsync(N2, 0, 16, stream);       // zero n^2 accumulators only

    transpose_x<<<Rn, 256, 0, stream>>>(X, XT);
    pass_kernel<1><<<960, 256, 0, stream>>>(XT, W, S, N2, PT, PL);
    combine_kernel<1><<<80, 256, 0, stream>>>(PT, PL, S + 0 * CBO, N2 + 0);
    pass_kernel<2><<<960, 256, 0, stream>>>(XT, W, S, N2, PT, PL);
    combine_kernel<2><<<80, 256, 0, stream>>>(PT, PL, S + 1 * CBO, N2 + 1);
    pass_kernel<3><<<960, 256, 0, stream>>>(XT, W, S, N2, PT, PL);
    combine_kernel<3><<<80, 256, 0, stream>>>(PT, PL, S + 2 * CBO, N2 + 2);
    final_kernel<<<80, 256, 0, stream>>>(S + 2 * CBO, N2 + 2, (float*)d_out);
}